// Round 5
// baseline (2084.988 us; speedup 1.0000x reference)
//
#include <hip/hip_runtime.h>
#include <math.h>

// SpectralGCN: GRU over T -> normalized Laplacian -> top-10 spectral filter
// (G=L*L^T, powers to G^32, 6x subspace applies with CholQR, Rayleigh-Ritz
//  one-barrier ping-pong Jacobi) -> 3 conv layers (factored M, W folded) ->
//  linear out fused into last update.
// Sizes: B=64, N=1024, F=8, T=12, H=32, K=10, OUT=12.

#define NN 1024
#define PP 48

// ---------------- GRU ----------------
__global__ __launch_bounds__(128) void k_gru(
    const float* __restrict__ x, const float* __restrict__ wih,
    const float* __restrict__ whh, const float* __restrict__ bih,
    const float* __restrict__ bhh, float* __restrict__ hout) {
  __shared__ float s_x[64][97];
  __shared__ float s_h[64][33];
  int tid = threadIdx.x;
  int row = tid & 63;
  int i_base = __builtin_amdgcn_readfirstlane((tid >> 6) * 16);
  long row0 = (long)blockIdx.x * 64;

  for (int i = tid; i < 64 * 24; i += 128) {
    int r = i / 24, c = i % 24;
    float4 v = *(const float4*)&x[(row0 + r) * 96 + c * 4];
    s_x[r][c * 4 + 0] = v.x; s_x[r][c * 4 + 1] = v.y;
    s_x[r][c * 4 + 2] = v.z; s_x[r][c * 4 + 3] = v.w;
  }
  for (int i = tid; i < 64 * 32; i += 128) s_h[i / 32][i % 32] = 0.f;
  __syncthreads();

  float h[32];
#pragma unroll
  for (int k = 0; k < 32; ++k) h[k] = 0.f;

  for (int t = 0; t < 12; ++t) {
    float x8[8];
#pragma unroll
    for (int f = 0; f < 8; ++f) x8[f] = s_x[row][f * 12 + t];
    for (int ii = 0; ii < 16; ++ii) {
      int i = i_base + ii;
      float ar = bih[i] + bhh[i];
      float az = bih[32 + i] + bhh[32 + i];
      float gx = bih[64 + i];
      float gh = bhh[64 + i];
#pragma unroll
      for (int f = 0; f < 8; ++f) {
        ar += x8[f] * wih[i * 8 + f];
        az += x8[f] * wih[(32 + i) * 8 + f];
        gx += x8[f] * wih[(64 + i) * 8 + f];
      }
#pragma unroll
      for (int k = 0; k < 32; ++k) {
        ar += h[k] * whh[i * 32 + k];
        az += h[k] * whh[(32 + i) * 32 + k];
        gh += h[k] * whh[(64 + i) * 32 + k];
      }
      float r = 1.f / (1.f + expf(-ar));
      float z = 1.f / (1.f + expf(-az));
      float n = tanhf(gx + r * gh);
      float hold = s_h[row][i];
      s_h[row][i] = (1.f - z) * n + z * hold;
    }
    __syncthreads();
#pragma unroll
    for (int k = 0; k < 32; ++k) h[k] = s_h[row][k];
    __syncthreads();
  }
  float* hp = hout + (row0 + row) * 32 + i_base;
#pragma unroll
  for (int k = 0; k < 16; k += 4) {
    float4 v = make_float4(h[i_base + k], h[i_base + k + 1],
                           h[i_base + k + 2], h[i_base + k + 3]);
    *(float4*)&hp[k] = v;
  }
}

// ---------------- graph build ----------------
__global__ void k_scatter(const int* __restrict__ ei, const float* __restrict__ ew,
                          float* __restrict__ A, int E) {
  int e = blockIdx.x * 256 + threadIdx.x;
  if (e < E) atomicAdd(&A[ei[e] * NN + ei[E + e]], ew[e]);
}

__global__ __launch_bounds__(256) void k_degree(const float* __restrict__ A,
                                                float* __restrict__ disq) {
  __shared__ float red[256];
  int row = blockIdx.x, tid = threadIdx.x;
  float s = 0.f;
  for (int j = tid; j < NN; j += 256) s += A[row * NN + j];
  red[tid] = s;
  __syncthreads();
  for (int off = 128; off > 0; off >>= 1) {
    if (tid < off) red[tid] += red[tid + off];
    __syncthreads();
  }
  if (tid == 0) disq[row] = 1.f / sqrtf(red[0]);
}

__global__ void k_lap(float* __restrict__ A, const float* __restrict__ disq) {
  int idx = blockIdx.x * 256 + threadIdx.x;
  int i = idx >> 10, j = idx & 1023;
  float v = -disq[i] * A[idx] * disq[j];
  if (i == j) v += 1.f;
  A[idx] = v;
}

// ---------------- C = A * B^T (1024^3 f32), reg-prefetch double buffer ----
__global__ __launch_bounds__(256) void k_mm_nt(const float* __restrict__ A,
                                               const float* __restrict__ B,
                                               float* __restrict__ C) {
  __shared__ float As[32][68];
  __shared__ float Bs[32][68];
  int tid = threadIdx.x;
  int tx = tid & 15, ty = tid >> 4;
  int i0 = blockIdx.y * 64, j0 = blockIdx.x * 64;
  float acc[4][4];
#pragma unroll
  for (int a = 0; a < 4; ++a)
#pragma unroll
    for (int b = 0; b < 4; ++b) acc[a][b] = 0.f;
  int lrow = tid >> 3;
  int kk0 = (tid & 7) * 4;
  float4 pa0 = *(const float4*)&A[(long)(i0 + lrow) * NN + kk0];
  float4 pa1 = *(const float4*)&A[(long)(i0 + lrow + 32) * NN + kk0];
  float4 pb0 = *(const float4*)&B[(long)(j0 + lrow) * NN + kk0];
  float4 pb1 = *(const float4*)&B[(long)(j0 + lrow + 32) * NN + kk0];
  for (int k0 = 0; k0 < NN; k0 += 32) {
    As[kk0 + 0][lrow] = pa0.x; As[kk0 + 1][lrow] = pa0.y;
    As[kk0 + 2][lrow] = pa0.z; As[kk0 + 3][lrow] = pa0.w;
    As[kk0 + 0][lrow + 32] = pa1.x; As[kk0 + 1][lrow + 32] = pa1.y;
    As[kk0 + 2][lrow + 32] = pa1.z; As[kk0 + 3][lrow + 32] = pa1.w;
    Bs[kk0 + 0][lrow] = pb0.x; Bs[kk0 + 1][lrow] = pb0.y;
    Bs[kk0 + 2][lrow] = pb0.z; Bs[kk0 + 3][lrow] = pb0.w;
    Bs[kk0 + 0][lrow + 32] = pb1.x; Bs[kk0 + 1][lrow + 32] = pb1.y;
    Bs[kk0 + 2][lrow + 32] = pb1.z; Bs[kk0 + 3][lrow + 32] = pb1.w;
    __syncthreads();
    if (k0 + 32 < NN) {
      pa0 = *(const float4*)&A[(long)(i0 + lrow) * NN + k0 + 32 + kk0];
      pa1 = *(const float4*)&A[(long)(i0 + lrow + 32) * NN + k0 + 32 + kk0];
      pb0 = *(const float4*)&B[(long)(j0 + lrow) * NN + k0 + 32 + kk0];
      pb1 = *(const float4*)&B[(long)(j0 + lrow + 32) * NN + k0 + 32 + kk0];
    }
#pragma unroll
    for (int kk = 0; kk < 32; ++kk) {
      float4 av = *(const float4*)&As[kk][ty * 4];
      float4 bv = *(const float4*)&Bs[kk][tx * 4];
      float aa[4] = {av.x, av.y, av.z, av.w};
      float bb[4] = {bv.x, bv.y, bv.z, bv.w};
#pragma unroll
      for (int a = 0; a < 4; ++a)
#pragma unroll
        for (int b = 0; b < 4; ++b) acc[a][b] += aa[a] * bb[b];
    }
    __syncthreads();
  }
#pragma unroll
  for (int a = 0; a < 4; ++a) {
    float4 v = make_float4(acc[a][0], acc[a][1], acc[a][2], acc[a][3]);
    *(float4*)&C[(long)(i0 + ty * 4 + a) * NN + j0 + tx * 4] = v;
  }
}

// ---------------- subspace iteration ----------------
__global__ void k_q0(float* __restrict__ Q) {
  int i = blockIdx.x * 256 + threadIdx.x;
  if (i < NN * PP) {
    unsigned u = (unsigned)i * 2654435761u;
    u ^= u >> 16; u *= 2246822519u; u ^= u >> 13; u *= 3266489917u; u ^= u >> 16;
    Q[i] = (float)(u & 0xFFFFFF) * (1.f / 16777216.f) - 0.5f;
  }
}

__global__ __launch_bounds__(256) void k_spmm(const float* __restrict__ Gp,
                                              const float* __restrict__ Q,
                                              float* __restrict__ Zp) {
  __shared__ float Qs[64][49];
  __shared__ float Gs[16][65];
  int tid = threadIdx.x;
  int r = tid >> 4;
  int c0 = (tid & 15) * 3;
  int row0 = blockIdx.x * 16;
  int k0 = blockIdx.y * 256;
  float a0 = 0.f, a1 = 0.f, a2 = 0.f;
  for (int kt = 0; kt < 4; ++kt) {
    int kb = k0 + kt * 64;
    for (int idx = tid; idx < 64 * PP; idx += 256) {
      int qr = idx / PP, qc = idx % PP;
      Qs[qr][qc] = Q[(kb + qr) * PP + qc];
    }
    for (int idx = tid; idx < 16 * 64; idx += 256) {
      int gr = idx >> 6, gk = idx & 63;
      Gs[gr][gk] = Gp[(long)(row0 + gr) * NN + kb + gk];
    }
    __syncthreads();
#pragma unroll 4
    for (int kk = 0; kk < 64; ++kk) {
      float g = Gs[r][kk];
      a0 += g * Qs[kk][c0];
      a1 += g * Qs[kk][c0 + 1];
      a2 += g * Qs[kk][c0 + 2];
    }
    __syncthreads();
  }
  float* zp = Zp + (long)blockIdx.y * (NN * PP);
  zp[(row0 + r) * PP + c0] = a0;
  zp[(row0 + r) * PP + c0 + 1] = a1;
  zp[(row0 + r) * PP + c0 + 2] = a2;
}

// Sum 4 partials -> Z, per-block Gram partial Sp[blk].
__global__ __launch_bounds__(256) void k_gram(const float* __restrict__ Zp,
                                              float* __restrict__ Z,
                                              float* __restrict__ Sp) {
  __shared__ float Zs[32][49];
  int tid = threadIdx.x;
  int r0 = blockIdx.x * 32;
  for (int idx = tid; idx < 32 * PP; idx += 256) {
    int r = idx / PP, c = idx % PP;
    long g = (long)(r0 + r) * PP + c;
    float s = Zp[g] + Zp[g + NN * PP] + Zp[g + 2 * NN * PP] + Zp[g + 3 * NN * PP];
    Zs[r][c] = s;
    Z[g] = s;
  }
  __syncthreads();
  float* sp = Sp + blockIdx.x * (PP * PP);
  for (int cell = tid; cell < PP * PP; cell += 256) {
    int i = cell / PP, j = cell % PP;
    float a = 0.f;
#pragma unroll 8
    for (int r = 0; r < 32; ++r) a += Zs[r][i] * Zs[r][j];
    sp[cell] = a;
  }
}

__global__ __launch_bounds__(256) void k_tbuild(const float* __restrict__ Qa,
                                                const float* __restrict__ Zp,
                                                float* __restrict__ Tp) {
  __shared__ float Qs[32][49];
  __shared__ float Ys[32][49];
  int tid = threadIdx.x;
  int r0 = blockIdx.x * 32;
  for (int idx = tid; idx < 32 * PP; idx += 256) {
    int r = idx / PP, c = idx % PP;
    long g = (long)(r0 + r) * PP + c;
    Qs[r][c] = Qa[g];
    Ys[r][c] = Zp[g] + Zp[g + NN * PP] + Zp[g + 2 * NN * PP] + Zp[g + 3 * NN * PP];
  }
  __syncthreads();
  float* tp = Tp + blockIdx.x * (PP * PP);
  for (int cell = tid; cell < PP * PP; cell += 256) {
    int i = cell / PP, j = cell % PP;
    float a = 0.f;
#pragma unroll 8
    for (int r = 0; r < 32; ++r) a += Qs[r][i] * Ys[r][j];
    tp[cell] = a;
  }
}

// Fused CholQR apply: each of 4 blocks redundantly factorizes S=R^T R, then
// its 256 rows solve y R = q in registers (no Rinv built). Q updated in place.
__global__ __launch_bounds__(256) void k_qr(const float* __restrict__ Sp,
                                            float* __restrict__ Q) {
  __shared__ float R[PP][PP + 1];
  __shared__ float rs[PP];
  __shared__ float idiag[PP];
  int tid = threadIdx.x;
  for (int idx = tid; idx < PP * PP; idx += 256) {
    float s = 0.f;
    for (int b = 0; b < 32; ++b) s += Sp[b * (PP * PP) + idx];
    R[idx / PP][idx % PP] = s;
  }
  __syncthreads();
  for (int j = 0; j < PP; ++j) {
    float d = R[j][j];
    float sq = sqrtf(d > 1e-30f ? d : 1e-30f);
    float invd = 1.f / sq;
    for (int c = j + tid; c < PP; c += 256)
      rs[c] = (c == j) ? sq : R[j][c] * invd;
    __syncthreads();
    int m = PP - 1 - j;
    for (int idx = tid; idx < m * m; idx += 256) {
      int i = j + 1 + idx / m, c = j + 1 + idx % m;
      R[i][c] -= rs[i] * rs[c];
    }
    for (int c = j + tid; c < PP; c += 256) R[j][c] = rs[c];
    __syncthreads();
  }
  if (tid < PP) idiag[tid] = 1.f / R[tid][tid];
  __syncthreads();
  int row = blockIdx.x * 256 + tid;
  float q[PP];
#pragma unroll
  for (int k = 0; k < PP; ++k) q[k] = Q[row * PP + k];
  // forward solve y R = q  (y_c = (q_c - sum_{k<c} y_k R[k][c]) / R[c][c])
#pragma unroll
  for (int c = 0; c < PP; ++c) {
    float s = q[c];
#pragma unroll
    for (int k = 0; k < c; ++k) s -= q[k] * R[k][c];
    q[c] = s * idiag[c];
  }
#pragma unroll
  for (int k = 0; k < PP; ++k) Q[row * PP + k] = q[k];
}

// One-barrier ping-pong cyclic Jacobi on 48x48, 6 sweeps; top-10 select.
// Each thread derives its rotation coefficients from the round-robin inverse
// mapping (no serial coefficient phase, no second barrier).
__global__ __launch_bounds__(384) void k_jacobi(const float* __restrict__ Tp,
                                                float* __restrict__ Vsel,
                                                float* __restrict__ s10) {
  __shared__ float Ta[PP][PP + 1], Tb[PP][PP + 1];
  __shared__ float Va[PP][PP + 1], Vb[PP][PP + 1];
  __shared__ int selidx[10];
  int tid = threadIdx.x;
  for (int idx = tid; idx < PP * PP; idx += 384) {
    float s = 0.f;
    for (int b = 0; b < 32; ++b) s += Tp[b * (PP * PP) + idx];
    Tb[idx / PP][idx % PP] = s;
  }
  __syncthreads();
  for (int idx = tid; idx < PP * PP; idx += 384) {
    int i = idx / PP, j = idx % PP;
    Ta[i][j] = 0.5f * (Tb[i][j] + Tb[j][i]);
    Va[i][j] = (i == j) ? 1.f : 0.f;
  }
  __syncthreads();
  float (*Tc)[PP + 1] = Ta, (*Tn)[PP + 1] = Tb;
  float (*Vc)[PP + 1] = Va, (*Vn)[PP + 1] = Vb;
  int i_row = tid >> 3;
  int jb = (tid & 7) * 6;

  // partner/role in round r (round-robin tournament, 0 fixed)
  auto pair_of = [](int j, int r, int& partner, bool& isp) {
    if (j == 0) {
      int v = r + 46; if (v >= 47) v -= 47;
      partner = v + 1; isp = true; return;
    }
    int a = j - 1 - r; if (a < 0) a += 47;
    if (a == 46) { partner = 0; isp = false; return; }
    int v = r + 45 - a; if (v >= 47) v -= 47;
    partner = v + 1; isp = (a < 23);
  };

  for (int sweep = 0; sweep < 6; ++sweep) {
    for (int r = 0; r < PP - 1; ++r) {
      // row rotation for i_row
      int prt; bool isp;
      pair_of(i_row, r, prt, isp);
      int pi = isp ? i_row : prt, qi = isp ? prt : i_row;
      float app = Tc[pi][pi], aqq = Tc[qi][qi], apq = Tc[pi][qi];
      float c = 1.f, s = 0.f;
      if (fabsf(apq) > 1e-30f) {
        float tau = (aqq - app) / (2.f * apq);
        float den = fabsf(tau) + sqrtf(1.f + tau * tau);
        float tt = copysignf(1.f / den, tau);
        c = 1.f / sqrtf(1.f + tt * tt);
        s = tt * c;
      }
      float wi0 = isp ? c : s, wi1 = isp ? -s : c;
      float tnew[6], vnew[6];
#pragma unroll
      for (int m = 0; m < 6; ++m) {
        int j = jb + m;
        int prtj; bool ispj;
        pair_of(j, r, prtj, ispj);
        int pj = ispj ? j : prtj, qj = ispj ? prtj : j;
        float bpp = Tc[pj][pj], bqq = Tc[qj][qj], bpq = Tc[pj][qj];
        float cj = 1.f, sj = 0.f;
        if (fabsf(bpq) > 1e-30f) {
          float tau = (bqq - bpp) / (2.f * bpq);
          float den = fabsf(tau) + sqrtf(1.f + tau * tau);
          float tt = copysignf(1.f / den, tau);
          cj = 1.f / sqrtf(1.f + tt * tt);
          sj = tt * cj;
        }
        float wj0 = ispj ? cj : sj, wj1 = ispj ? -sj : cj;
        tnew[m] = wi0 * (wj0 * Tc[pi][pj] + wj1 * Tc[pi][qj]) +
                  wi1 * (wj0 * Tc[qi][pj] + wj1 * Tc[qi][qj]);
        vnew[m] = wj0 * Vc[i_row][pj] + wj1 * Vc[i_row][qj];
      }
#pragma unroll
      for (int m = 0; m < 6; ++m) {
        Tn[i_row][jb + m] = tnew[m];
        Vn[i_row][jb + m] = vnew[m];
      }
      __syncthreads();
      float (*tt_)[PP + 1] = Tc; Tc = Tn; Tn = tt_;
      float (*vt_)[PP + 1] = Vc; Vc = Vn; Vn = vt_;
    }
  }
  // wave-0 top-10 selection via shfl butterfly (deterministic tie-break)
  if (tid < 64) {
    float v = (tid < PP) ? Tc[tid][tid] : -1e30f;
    for (int sel = 0; sel < 10; ++sel) {
      float bv = v; int bi = tid;
      for (int off = 32; off > 0; off >>= 1) {
        float ov = __shfl_xor(bv, off);
        int oi = __shfl_xor(bi, off);
        if (ov > bv || (ov == bv && oi < bi)) { bv = ov; bi = oi; }
      }
      if (tid == 0) {
        selidx[sel] = bi;
        s10[sel] = sqrtf(fmaxf(bv, 0.f));
      }
      if (tid == bi) v = -1e30f;
    }
  }
  __syncthreads();
  for (int idx = tid; idx < PP * 10; idx += 384) {
    int j = idx / 10, i = idx % 10;
    Vsel[idx] = Vc[j][selidx[i]];
  }
}

// U10 = Qa * Vsel. grid 4 x 256.
__global__ __launch_bounds__(256) void k_u10(const float* __restrict__ Q,
                                             const float* __restrict__ Vsel,
                                             float* __restrict__ U10) {
  __shared__ float Vs[PP * 10];
  int tid = threadIdx.x;
  for (int idx = tid; idx < PP * 10; idx += 256) Vs[idx] = Vsel[idx];
  __syncthreads();
  int row = blockIdx.x * 256 + tid;
  float q[PP];
#pragma unroll
  for (int k = 0; k < PP; ++k) q[k] = Q[row * PP + k];
#pragma unroll
  for (int i = 0; i < 10; ++i) {
    float s = 0.f;
#pragma unroll
    for (int k = 0; k < PP; ++k) s += q[k] * Vs[k * 10 + i];
    U10[row * 10 + i] = s;
  }
}

// ---------------- conv layers ----------------
// P1[b,i,k] = s10[i] * sum_j (sum_n U10[n,i] h[b,n,j]) W[j,k]
__global__ __launch_bounds__(320) void k_p0w(const float* __restrict__ h,
                                             const float* __restrict__ U10,
                                             const float* __restrict__ W,
                                             const float* __restrict__ s10,
                                             float* __restrict__ P1) {
  __shared__ float Hs[128][33];
  __shared__ float Us[128][10];
  __shared__ float P0s[10][33];
  __shared__ float Ws[32][32];
  int tid = threadIdx.x;
  int b = blockIdx.x;
  int i = tid / 32, kk = tid % 32;
  for (int idx = tid; idx < 1024; idx += 320) Ws[idx / 32][idx % 32] = W[idx];
  float acc = 0.f;
  for (int t0 = 0; t0 < NN; t0 += 128) {
    for (int idx = tid; idx < 128 * 32; idx += 320) {
      int r = idx / 32, c = idx % 32;
      Hs[r][c] = h[(long)(b * NN + t0 + r) * 32 + c];
    }
    for (int idx = tid; idx < 1280; idx += 320) {
      Us[idx / 10][idx % 10] = U10[(t0 + idx / 10) * 10 + idx % 10];
    }
    __syncthreads();
#pragma unroll 8
    for (int r = 0; r < 128; ++r) acc += Us[r][i] * Hs[r][kk];
    __syncthreads();
  }
  P0s[i][kk] = acc;
  __syncthreads();
  float a = 0.f;
#pragma unroll
  for (int j = 0; j < 32; ++j) a += P0s[i][j] * Ws[j][kk];
  P1[b * 320 + i * 32 + kk] = s10[i] * a;
}

// h += relu(U10 * P1); LAST layer also emits out = h_new @ lw + lb.
template <int LAST>
__global__ __launch_bounds__(256) void k_update(float* __restrict__ h,
                                                const float* __restrict__ U10,
                                                const float* __restrict__ P1,
                                                const float* __restrict__ lw,
                                                const float* __restrict__ lb,
                                                float* __restrict__ out) {
  __shared__ float a1[10][32];
  __shared__ float Us[64][10];
  __shared__ float hl[64][33];
  int tid = threadIdx.x;
  int b = blockIdx.x, n0 = blockIdx.y * 64;
  for (int idx = tid; idx < 320; idx += 256)
    a1[idx / 32][idx % 32] = P1[b * 320 + idx];
  for (int idx = tid; idx < 640; idx += 256)
    Us[idx / 10][idx % 10] = U10[(n0 + idx / 10) * 10 + idx % 10];
  __syncthreads();
  for (int idx = tid; idx < 2048; idx += 256) {
    int nl = idx / 32, k = idx % 32;
    float z = 0.f;
#pragma unroll
    for (int i = 0; i < 10; ++i) z += Us[nl][i] * a1[i][k];
    long g = (long)(b * NN + n0 + nl) * 32 + k;
    float hn = h[g] + fmaxf(z, 0.f);
    if (LAST) hl[nl][k] = hn;
    else h[g] = hn;
  }
  if (LAST) {
    __syncthreads();
    for (int idx = tid; idx < 64 * 12; idx += 256) {
      int row = idx / 12, o = idx % 12;
      float s = lb[o];
#pragma unroll
      for (int j = 0; j < 32; ++j) s += hl[row][j] * lw[j * 12 + o];
      out[(long)(b * NN + n0 + row) * 12 + o] = s;
    }
  }
}

extern "C" void kernel_launch(void* const* d_in, const int* in_sizes, int n_in,
                              void* d_out, int out_size, void* d_ws, size_t ws_size,
                              hipStream_t stream) {
  const float* x    = (const float*)d_in[0];
  const int*   ei   = (const int*)d_in[1];
  const float* ew   = (const float*)d_in[2];
  const float* wih  = (const float*)d_in[3];
  const float* whh  = (const float*)d_in[4];
  const float* bih  = (const float*)d_in[5];
  const float* bhh  = (const float*)d_in[6];
  const float* convw = (const float*)d_in[7];
  const float* lw   = (const float*)d_in[8];
  const float* lb   = (const float*)d_in[9];
  float* out = (float*)d_out;
  float* ws  = (float*)d_ws;
  int E = in_sizes[1] / 2;

  // workspace layout (floats), ~22.9 MB
  float* h    = ws;                 // 2097152
  float* B1   = h + 2097152;        // 1048576
  float* B2   = B1 + 1048576;       // 1048576
  float* B3   = B2 + 1048576;       // 1048576
  float* Qa   = B3 + 1048576;       // 49152
  float* Qb   = Qa + 49152;         // 49152
  float* Zp   = Qb + 49152;         // 196608
  float* Sp   = Zp + 196608;        // 73728
  float* Tp   = Sp + 73728;         // 73728
  float* Vsel = Tp + 73728;         // 480
  float* s10  = Vsel + 480;         // 16
  float* U10  = s10 + 16;           // 10240
  float* P1   = U10 + 10240;        // 20480
  float* disq = P1 + 20480;         // 1024

  // Stage A: GRU
  k_gru<<<1024, 128, 0, stream>>>(x, wih, whh, bih, bhh, h);

  // Stage B: Laplacian (B1) and powers: B2=G, B3=G^32
  hipMemsetAsync(B1, 0, (size_t)1048576 * 4, stream);
  k_scatter<<<(E + 255) / 256, 256, 0, stream>>>(ei, ew, B1, E);
  k_degree<<<NN, 256, 0, stream>>>(B1, disq);
  k_lap<<<4096, 256, 0, stream>>>(B1, disq);
  k_mm_nt<<<dim3(16, 16), 256, 0, stream>>>(B1, B1, B2);  // G
  k_mm_nt<<<dim3(16, 16), 256, 0, stream>>>(B2, B2, B3);  // G^2
  k_mm_nt<<<dim3(16, 16), 256, 0, stream>>>(B3, B3, B1);  // G^4
  k_mm_nt<<<dim3(16, 16), 256, 0, stream>>>(B1, B1, B3);  // G^8
  k_mm_nt<<<dim3(16, 16), 256, 0, stream>>>(B3, B3, B1);  // G^16
  k_mm_nt<<<dim3(16, 16), 256, 0, stream>>>(B1, B1, B3);  // G^32

  // Stage C: 6 applies of G^32 (=192 powers), CholQR after each
  k_q0<<<192, 256, 0, stream>>>(Qa);
  for (int it = 0; it < 6; ++it) {
    float* src = (it & 1) ? Qb : Qa;
    float* dst = (it & 1) ? Qa : Qb;
    k_spmm<<<dim3(64, 4), 256, 0, stream>>>(B3, src, Zp);
    k_gram<<<32, 256, 0, stream>>>(Zp, dst, Sp);
    k_qr<<<4, 256, 0, stream>>>(Sp, dst);
  }
  // final orthonormal basis in Qa

  // Rayleigh-Ritz with G
  k_spmm<<<dim3(64, 4), 256, 0, stream>>>(B2, Qa, Zp);
  k_tbuild<<<32, 256, 0, stream>>>(Qa, Zp, Tp);
  k_jacobi<<<1, 384, 0, stream>>>(Tp, Vsel, s10);
  k_u10<<<4, 256, 0, stream>>>(Qa, Vsel, U10);

  // Stage D: conv layers (W folded into projection), out fused into last
  for (int l = 0; l < 3; ++l) {
    k_p0w<<<64, 320, 0, stream>>>(h, U10, convw + l * 1024, s10, P1);
    if (l < 2)
      k_update<0><<<dim3(64, 16), 256, 0, stream>>>(h, U10, P1, lw, lb, out);
    else
      k_update<1><<<dim3(64, 16), 256, 0, stream>>>(h, U10, P1, lw, lb, out);
  }
}

// Round 6
// 1361.345 us; speedup vs baseline: 1.5316x; 1.5316x over previous
//
#include <hip/hip_runtime.h>
#include <math.h>

// SpectralGCN: GRU over T -> normalized Laplacian -> top-10 spectral filter
// (G=L*L^T, powers to G^32, 6x subspace applies with CholQR, Rayleigh-Ritz
//  2-barrier shared-coefficient Jacobi, 3 sweeps) -> 3 conv layers (factored
//  M, W folded) -> linear out fused into last update.
// Sizes: B=64, N=1024, F=8, T=12, H=32, K=10, OUT=12.

#define NN 1024
#define PP 48
#define JSWEEPS 3

// ---------------- GRU ----------------
__global__ __launch_bounds__(128) void k_gru(
    const float* __restrict__ x, const float* __restrict__ wih,
    const float* __restrict__ whh, const float* __restrict__ bih,
    const float* __restrict__ bhh, float* __restrict__ hout) {
  __shared__ float s_x[64][97];
  __shared__ float s_h[64][33];
  int tid = threadIdx.x;
  int row = tid & 63;
  int i_base = __builtin_amdgcn_readfirstlane((tid >> 6) * 16);
  long row0 = (long)blockIdx.x * 64;

  for (int i = tid; i < 64 * 24; i += 128) {
    int r = i / 24, c = i % 24;
    float4 v = *(const float4*)&x[(row0 + r) * 96 + c * 4];
    s_x[r][c * 4 + 0] = v.x; s_x[r][c * 4 + 1] = v.y;
    s_x[r][c * 4 + 2] = v.z; s_x[r][c * 4 + 3] = v.w;
  }
  for (int i = tid; i < 64 * 32; i += 128) s_h[i / 32][i % 32] = 0.f;
  __syncthreads();

  float h[32];
#pragma unroll
  for (int k = 0; k < 32; ++k) h[k] = 0.f;

  for (int t = 0; t < 12; ++t) {
    float x8[8];
#pragma unroll
    for (int f = 0; f < 8; ++f) x8[f] = s_x[row][f * 12 + t];
    for (int ii = 0; ii < 16; ++ii) {
      int i = i_base + ii;
      float ar = bih[i] + bhh[i];
      float az = bih[32 + i] + bhh[32 + i];
      float gx = bih[64 + i];
      float gh = bhh[64 + i];
#pragma unroll
      for (int f = 0; f < 8; ++f) {
        ar += x8[f] * wih[i * 8 + f];
        az += x8[f] * wih[(32 + i) * 8 + f];
        gx += x8[f] * wih[(64 + i) * 8 + f];
      }
#pragma unroll
      for (int k = 0; k < 32; ++k) {
        ar += h[k] * whh[i * 32 + k];
        az += h[k] * whh[(32 + i) * 32 + k];
        gh += h[k] * whh[(64 + i) * 32 + k];
      }
      float r = 1.f / (1.f + expf(-ar));
      float z = 1.f / (1.f + expf(-az));
      float n = tanhf(gx + r * gh);
      float hold = s_h[row][i];
      s_h[row][i] = (1.f - z) * n + z * hold;
    }
    __syncthreads();
#pragma unroll
    for (int k = 0; k < 32; ++k) h[k] = s_h[row][k];
    __syncthreads();
  }
  float* hp = hout + (row0 + row) * 32 + i_base;
#pragma unroll
  for (int k = 0; k < 16; k += 4) {
    float4 v = make_float4(h[i_base + k], h[i_base + k + 1],
                           h[i_base + k + 2], h[i_base + k + 3]);
    *(float4*)&hp[k] = v;
  }
}

// ---------------- graph build ----------------
__global__ void k_scatter(const int* __restrict__ ei, const float* __restrict__ ew,
                          float* __restrict__ A, int E) {
  int e = blockIdx.x * 256 + threadIdx.x;
  if (e < E) atomicAdd(&A[ei[e] * NN + ei[E + e]], ew[e]);
}

__global__ __launch_bounds__(256) void k_degree(const float* __restrict__ A,
                                                float* __restrict__ disq) {
  __shared__ float red[256];
  int row = blockIdx.x, tid = threadIdx.x;
  float s = 0.f;
  for (int j = tid; j < NN; j += 256) s += A[row * NN + j];
  red[tid] = s;
  __syncthreads();
  for (int off = 128; off > 0; off >>= 1) {
    if (tid < off) red[tid] += red[tid + off];
    __syncthreads();
  }
  if (tid == 0) disq[row] = 1.f / sqrtf(red[0]);
}

__global__ void k_lap(float* __restrict__ A, const float* __restrict__ disq) {
  int idx = blockIdx.x * 256 + threadIdx.x;
  int i = idx >> 10, j = idx & 1023;
  float v = -disq[i] * A[idx] * disq[j];
  if (i == j) v += 1.f;
  A[idx] = v;
}

// ---------------- C = A * B^T (1024^3 f32), reg-prefetch double buffer ----
__global__ __launch_bounds__(256) void k_mm_nt(const float* __restrict__ A,
                                               const float* __restrict__ B,
                                               float* __restrict__ C) {
  __shared__ float As[32][68];
  __shared__ float Bs[32][68];
  int tid = threadIdx.x;
  int tx = tid & 15, ty = tid >> 4;
  int i0 = blockIdx.y * 64, j0 = blockIdx.x * 64;
  float acc[4][4];
#pragma unroll
  for (int a = 0; a < 4; ++a)
#pragma unroll
    for (int b = 0; b < 4; ++b) acc[a][b] = 0.f;
  int lrow = tid >> 3;
  int kk0 = (tid & 7) * 4;
  float4 pa0 = *(const float4*)&A[(long)(i0 + lrow) * NN + kk0];
  float4 pa1 = *(const float4*)&A[(long)(i0 + lrow + 32) * NN + kk0];
  float4 pb0 = *(const float4*)&B[(long)(j0 + lrow) * NN + kk0];
  float4 pb1 = *(const float4*)&B[(long)(j0 + lrow + 32) * NN + kk0];
  for (int k0 = 0; k0 < NN; k0 += 32) {
    As[kk0 + 0][lrow] = pa0.x; As[kk0 + 1][lrow] = pa0.y;
    As[kk0 + 2][lrow] = pa0.z; As[kk0 + 3][lrow] = pa0.w;
    As[kk0 + 0][lrow + 32] = pa1.x; As[kk0 + 1][lrow + 32] = pa1.y;
    As[kk0 + 2][lrow + 32] = pa1.z; As[kk0 + 3][lrow + 32] = pa1.w;
    Bs[kk0 + 0][lrow] = pb0.x; Bs[kk0 + 1][lrow] = pb0.y;
    Bs[kk0 + 2][lrow] = pb0.z; Bs[kk0 + 3][lrow] = pb0.w;
    Bs[kk0 + 0][lrow + 32] = pb1.x; Bs[kk0 + 1][lrow + 32] = pb1.y;
    Bs[kk0 + 2][lrow + 32] = pb1.z; Bs[kk0 + 3][lrow + 32] = pb1.w;
    __syncthreads();
    if (k0 + 32 < NN) {
      pa0 = *(const float4*)&A[(long)(i0 + lrow) * NN + k0 + 32 + kk0];
      pa1 = *(const float4*)&A[(long)(i0 + lrow + 32) * NN + k0 + 32 + kk0];
      pb0 = *(const float4*)&B[(long)(j0 + lrow) * NN + k0 + 32 + kk0];
      pb1 = *(const float4*)&B[(long)(j0 + lrow + 32) * NN + k0 + 32 + kk0];
    }
#pragma unroll
    for (int kk = 0; kk < 32; ++kk) {
      float4 av = *(const float4*)&As[kk][ty * 4];
      float4 bv = *(const float4*)&Bs[kk][tx * 4];
      float aa[4] = {av.x, av.y, av.z, av.w};
      float bb[4] = {bv.x, bv.y, bv.z, bv.w};
#pragma unroll
      for (int a = 0; a < 4; ++a)
#pragma unroll
        for (int b = 0; b < 4; ++b) acc[a][b] += aa[a] * bb[b];
    }
    __syncthreads();
  }
#pragma unroll
  for (int a = 0; a < 4; ++a) {
    float4 v = make_float4(acc[a][0], acc[a][1], acc[a][2], acc[a][3]);
    *(float4*)&C[(long)(i0 + ty * 4 + a) * NN + j0 + tx * 4] = v;
  }
}

// ---------------- subspace iteration ----------------
__global__ void k_q0(float* __restrict__ Q) {
  int i = blockIdx.x * 256 + threadIdx.x;
  if (i < NN * PP) {
    unsigned u = (unsigned)i * 2654435761u;
    u ^= u >> 16; u *= 2246822519u; u ^= u >> 13; u *= 3266489917u; u ^= u >> 16;
    Q[i] = (float)(u & 0xFFFFFF) * (1.f / 16777216.f) - 0.5f;
  }
}

__global__ __launch_bounds__(256) void k_spmm(const float* __restrict__ Gp,
                                              const float* __restrict__ Q,
                                              float* __restrict__ Zp) {
  __shared__ float Qs[64][49];
  __shared__ float Gs[16][65];
  int tid = threadIdx.x;
  int r = tid >> 4;
  int c0 = (tid & 15) * 3;
  int row0 = blockIdx.x * 16;
  int k0 = blockIdx.y * 256;
  float a0 = 0.f, a1 = 0.f, a2 = 0.f;
  for (int kt = 0; kt < 4; ++kt) {
    int kb = k0 + kt * 64;
    for (int idx = tid; idx < 64 * PP; idx += 256) {
      int qr = idx / PP, qc = idx % PP;
      Qs[qr][qc] = Q[(kb + qr) * PP + qc];
    }
    for (int idx = tid; idx < 16 * 64; idx += 256) {
      int gr = idx >> 6, gk = idx & 63;
      Gs[gr][gk] = Gp[(long)(row0 + gr) * NN + kb + gk];
    }
    __syncthreads();
#pragma unroll 4
    for (int kk = 0; kk < 64; ++kk) {
      float g = Gs[r][kk];
      a0 += g * Qs[kk][c0];
      a1 += g * Qs[kk][c0 + 1];
      a2 += g * Qs[kk][c0 + 2];
    }
    __syncthreads();
  }
  float* zp = Zp + (long)blockIdx.y * (NN * PP);
  zp[(row0 + r) * PP + c0] = a0;
  zp[(row0 + r) * PP + c0 + 1] = a1;
  zp[(row0 + r) * PP + c0 + 2] = a2;
}

// Sum 4 partials -> Z, per-block Gram partial Sp[blk].
__global__ __launch_bounds__(256) void k_gram(const float* __restrict__ Zp,
                                              float* __restrict__ Z,
                                              float* __restrict__ Sp) {
  __shared__ float Zs[32][49];
  int tid = threadIdx.x;
  int r0 = blockIdx.x * 32;
  for (int idx = tid; idx < 32 * PP; idx += 256) {
    int r = idx / PP, c = idx % PP;
    long g = (long)(r0 + r) * PP + c;
    float s = Zp[g] + Zp[g + NN * PP] + Zp[g + 2 * NN * PP] + Zp[g + 3 * NN * PP];
    Zs[r][c] = s;
    Z[g] = s;
  }
  __syncthreads();
  float* sp = Sp + blockIdx.x * (PP * PP);
  for (int cell = tid; cell < PP * PP; cell += 256) {
    int i = cell / PP, j = cell % PP;
    float a = 0.f;
#pragma unroll 8
    for (int r = 0; r < 32; ++r) a += Zs[r][i] * Zs[r][j];
    sp[cell] = a;
  }
}

__global__ __launch_bounds__(256) void k_tbuild(const float* __restrict__ Qa,
                                                const float* __restrict__ Zp,
                                                float* __restrict__ Tp) {
  __shared__ float Qs[32][49];
  __shared__ float Ys[32][49];
  int tid = threadIdx.x;
  int r0 = blockIdx.x * 32;
  for (int idx = tid; idx < 32 * PP; idx += 256) {
    int r = idx / PP, c = idx % PP;
    long g = (long)(r0 + r) * PP + c;
    Qs[r][c] = Qa[g];
    Ys[r][c] = Zp[g] + Zp[g + NN * PP] + Zp[g + 2 * NN * PP] + Zp[g + 3 * NN * PP];
  }
  __syncthreads();
  float* tp = Tp + blockIdx.x * (PP * PP);
  for (int cell = tid; cell < PP * PP; cell += 256) {
    int i = cell / PP, j = cell % PP;
    float a = 0.f;
#pragma unroll 8
    for (int r = 0; r < 32; ++r) a += Qs[r][i] * Ys[r][j];
    tp[cell] = a;
  }
}

// Fused CholQR apply: each of 4 blocks redundantly factorizes S=R^T R, then
// its 256 rows solve y R = q in registers (no Rinv built). Q updated in place.
__global__ __launch_bounds__(256) void k_qr(const float* __restrict__ Sp,
                                            float* __restrict__ Q) {
  __shared__ float R[PP][PP + 1];
  __shared__ float rs[PP];
  __shared__ float idiag[PP];
  int tid = threadIdx.x;
  for (int idx = tid; idx < PP * PP; idx += 256) {
    float s = 0.f;
    for (int b = 0; b < 32; ++b) s += Sp[b * (PP * PP) + idx];
    R[idx / PP][idx % PP] = s;
  }
  __syncthreads();
  for (int j = 0; j < PP; ++j) {
    float d = R[j][j];
    float sq = sqrtf(d > 1e-30f ? d : 1e-30f);
    float invd = 1.f / sq;
    for (int c = j + tid; c < PP; c += 256)
      rs[c] = (c == j) ? sq : R[j][c] * invd;
    __syncthreads();
    int m = PP - 1 - j;
    for (int idx = tid; idx < m * m; idx += 256) {
      int i = j + 1 + idx / m, c = j + 1 + idx % m;
      R[i][c] -= rs[i] * rs[c];
    }
    for (int c = j + tid; c < PP; c += 256) R[j][c] = rs[c];
    __syncthreads();
  }
  if (tid < PP) idiag[tid] = 1.f / R[tid][tid];
  __syncthreads();
  int row = blockIdx.x * 256 + tid;
  float q[PP];
#pragma unroll
  for (int k = 0; k < PP; ++k) q[k] = Q[row * PP + k];
#pragma unroll
  for (int c = 0; c < PP; ++c) {
    float s = q[c];
#pragma unroll
    for (int k = 0; k < c; ++k) s -= q[k] * R[k][c];
    q[c] = s * idiag[c];
  }
#pragma unroll
  for (int k = 0; k < PP; ++k) Q[row * PP + k] = q[k];
}

// Shared-coefficient ping-pong cyclic Jacobi (2 barriers/round), JSWEEPS
// sweeps; top-10 select via wave-0 shfl butterfly. T is near-diagonal on
// entry (Qa from simultaneous iteration), so few sweeps suffice.
__global__ __launch_bounds__(384) void k_jacobi(const float* __restrict__ Tp,
                                                float* __restrict__ Vsel,
                                                float* __restrict__ s10) {
  __shared__ float Ta[PP][PP + 1], Tb[PP][PP + 1];
  __shared__ float Va[PP][PP + 1], Vb[PP][PP + 1];
  __shared__ float w0[PP], w1[PP];
  __shared__ int j0a[PP], j1a[PP];
  __shared__ int selidx[10];
  int tid = threadIdx.x;
  for (int idx = tid; idx < PP * PP; idx += 384) {
    float s = 0.f;
    for (int b = 0; b < 32; ++b) s += Tp[b * (PP * PP) + idx];
    Tb[idx / PP][idx % PP] = s;
  }
  __syncthreads();
  for (int idx = tid; idx < PP * PP; idx += 384) {
    int i = idx / PP, j = idx % PP;
    Ta[i][j] = 0.5f * (Tb[i][j] + Tb[j][i]);
    Va[i][j] = (i == j) ? 1.f : 0.f;
  }
  __syncthreads();
  float (*Tc)[PP + 1] = Ta, (*Tn)[PP + 1] = Tb;
  float (*Vc)[PP + 1] = Va, (*Vn)[PP + 1] = Vb;
  int i_row = tid >> 3;
  int jb = (tid & 7) * 6;
  for (int sweep = 0; sweep < JSWEEPS; ++sweep) {
    for (int r = 0; r < PP - 1; ++r) {
      if (tid < 24) {
        int k = tid;
        int p = (k == 0) ? 0 : ((r + k - 1) % 47) + 1;
        int q = ((r + 46 - k) % 47) + 1;
        float app = Tc[p][p], aqq = Tc[q][q], apq = Tc[p][q];
        float c = 1.f, s = 0.f;
        if (fabsf(apq) > 1e-30f) {
          float tau = (aqq - app) / (2.f * apq);
          float den = fabsf(tau) + sqrtf(1.f + tau * tau);
          float tt = copysignf(1.f / den, tau);
          c = 1.f / sqrtf(1.f + tt * tt);
          s = tt * c;
        }
        j0a[p] = p; j1a[p] = q; w0[p] = c;  w1[p] = -s;
        j0a[q] = p; j1a[q] = q; w0[q] = s;  w1[q] = c;
      }
      __syncthreads();
      float wi0 = w0[i_row], wi1 = w1[i_row];
      int i0 = j0a[i_row], i1 = j1a[i_row];
      float tnew[6], vnew[6];
#pragma unroll
      for (int m = 0; m < 6; ++m) {
        int j = jb + m;
        float wj0 = w0[j], wj1 = w1[j];
        int a = j0a[j], b = j1a[j];
        tnew[m] = wi0 * (wj0 * Tc[i0][a] + wj1 * Tc[i0][b]) +
                  wi1 * (wj0 * Tc[i1][a] + wj1 * Tc[i1][b]);
        vnew[m] = wj0 * Vc[i_row][a] + wj1 * Vc[i_row][b];
      }
#pragma unroll
      for (int m = 0; m < 6; ++m) {
        Tn[i_row][jb + m] = tnew[m];
        Vn[i_row][jb + m] = vnew[m];
      }
      __syncthreads();
      float (*tt_)[PP + 1] = Tc; Tc = Tn; Tn = tt_;
      float (*vt_)[PP + 1] = Vc; Vc = Vn; Vn = vt_;
    }
  }
  if (tid < 64) {
    float v = (tid < PP) ? Tc[tid][tid] : -1e30f;
    for (int sel = 0; sel < 10; ++sel) {
      float bv = v; int bi = tid;
      for (int off = 32; off > 0; off >>= 1) {
        float ov = __shfl_xor(bv, off);
        int oi = __shfl_xor(bi, off);
        if (ov > bv || (ov == bv && oi < bi)) { bv = ov; bi = oi; }
      }
      if (tid == 0) {
        selidx[sel] = bi;
        s10[sel] = sqrtf(fmaxf(bv, 0.f));
      }
      if (tid == bi) v = -1e30f;
    }
  }
  __syncthreads();
  for (int idx = tid; idx < PP * 10; idx += 384) {
    int j = idx / 10, i = idx % 10;
    Vsel[idx] = Vc[j][selidx[i]];
  }
}

// U10 = Qa * Vsel. grid 4 x 256.
__global__ __launch_bounds__(256) void k_u10(const float* __restrict__ Q,
                                             const float* __restrict__ Vsel,
                                             float* __restrict__ U10) {
  __shared__ float Vs[PP * 10];
  int tid = threadIdx.x;
  for (int idx = tid; idx < PP * 10; idx += 256) Vs[idx] = Vsel[idx];
  __syncthreads();
  int row = blockIdx.x * 256 + tid;
  float q[PP];
#pragma unroll
  for (int k = 0; k < PP; ++k) q[k] = Q[row * PP + k];
#pragma unroll
  for (int i = 0; i < 10; ++i) {
    float s = 0.f;
#pragma unroll
    for (int k = 0; k < PP; ++k) s += q[k] * Vs[k * 10 + i];
    U10[row * 10 + i] = s;
  }
}

// ---------------- conv layers ----------------
// P1[b,i,k] = s10[i] * sum_j (sum_n U10[n,i] h[b,n,j]) W[j,k]
__global__ __launch_bounds__(320) void k_p0w(const float* __restrict__ h,
                                             const float* __restrict__ U10,
                                             const float* __restrict__ W,
                                             const float* __restrict__ s10,
                                             float* __restrict__ P1) {
  __shared__ float Hs[128][33];
  __shared__ float Us[128][10];
  __shared__ float P0s[10][33];
  __shared__ float Ws[32][32];
  int tid = threadIdx.x;
  int b = blockIdx.x;
  int i = tid / 32, kk = tid % 32;
  for (int idx = tid; idx < 1024; idx += 320) Ws[idx / 32][idx % 32] = W[idx];
  float acc = 0.f;
  for (int t0 = 0; t0 < NN; t0 += 128) {
    for (int idx = tid; idx < 128 * 32; idx += 320) {
      int r = idx / 32, c = idx % 32;
      Hs[r][c] = h[(long)(b * NN + t0 + r) * 32 + c];
    }
    for (int idx = tid; idx < 1280; idx += 320) {
      Us[idx / 10][idx % 10] = U10[(t0 + idx / 10) * 10 + idx % 10];
    }
    __syncthreads();
#pragma unroll 8
    for (int r = 0; r < 128; ++r) acc += Us[r][i] * Hs[r][kk];
    __syncthreads();
  }
  P0s[i][kk] = acc;
  __syncthreads();
  float a = 0.f;
#pragma unroll
  for (int j = 0; j < 32; ++j) a += P0s[i][j] * Ws[j][kk];
  P1[b * 320 + i * 32 + kk] = s10[i] * a;
}

// h += relu(U10 * P1); LAST layer also emits out = h_new @ lw + lb.
template <int LAST>
__global__ __launch_bounds__(256) void k_update(float* __restrict__ h,
                                                const float* __restrict__ U10,
                                                const float* __restrict__ P1,
                                                const float* __restrict__ lw,
                                                const float* __restrict__ lb,
                                                float* __restrict__ out) {
  __shared__ float a1[10][32];
  __shared__ float Us[64][10];
  __shared__ float hl[64][33];
  int tid = threadIdx.x;
  int b = blockIdx.x, n0 = blockIdx.y * 64;
  for (int idx = tid; idx < 320; idx += 256)
    a1[idx / 32][idx % 32] = P1[b * 320 + idx];
  for (int idx = tid; idx < 640; idx += 256)
    Us[idx / 10][idx % 10] = U10[(n0 + idx / 10) * 10 + idx % 10];
  __syncthreads();
  for (int idx = tid; idx < 2048; idx += 256) {
    int nl = idx / 32, k = idx % 32;
    float z = 0.f;
#pragma unroll
    for (int i = 0; i < 10; ++i) z += Us[nl][i] * a1[i][k];
    long g = (long)(b * NN + n0 + nl) * 32 + k;
    float hn = h[g] + fmaxf(z, 0.f);
    if (LAST) hl[nl][k] = hn;
    else h[g] = hn;
  }
  if (LAST) {
    __syncthreads();
    for (int idx = tid; idx < 64 * 12; idx += 256) {
      int row = idx / 12, o = idx % 12;
      float s = lb[o];
#pragma unroll
      for (int j = 0; j < 32; ++j) s += hl[row][j] * lw[j * 12 + o];
      out[(long)(b * NN + n0 + row) * 12 + o] = s;
    }
  }
}

extern "C" void kernel_launch(void* const* d_in, const int* in_sizes, int n_in,
                              void* d_out, int out_size, void* d_ws, size_t ws_size,
                              hipStream_t stream) {
  const float* x    = (const float*)d_in[0];
  const int*   ei   = (const int*)d_in[1];
  const float* ew   = (const float*)d_in[2];
  const float* wih  = (const float*)d_in[3];
  const float* whh  = (const float*)d_in[4];
  const float* bih  = (const float*)d_in[5];
  const float* bhh  = (const float*)d_in[6];
  const float* convw = (const float*)d_in[7];
  const float* lw   = (const float*)d_in[8];
  const float* lb   = (const float*)d_in[9];
  float* out = (float*)d_out;
  float* ws  = (float*)d_ws;
  int E = in_sizes[1] / 2;

  // workspace layout (floats), ~22.9 MB
  float* h    = ws;                 // 2097152
  float* B1   = h + 2097152;        // 1048576
  float* B2   = B1 + 1048576;       // 1048576
  float* B3   = B2 + 1048576;       // 1048576
  float* Qa   = B3 + 1048576;       // 49152
  float* Qb   = Qa + 49152;         // 49152
  float* Zp   = Qb + 49152;         // 196608
  float* Sp   = Zp + 196608;        // 73728
  float* Tp   = Sp + 73728;         // 73728
  float* Vsel = Tp + 73728;         // 480
  float* s10  = Vsel + 480;         // 16
  float* U10  = s10 + 16;           // 10240
  float* P1   = U10 + 10240;        // 20480
  float* disq = P1 + 20480;         // 1024

  // Stage A: GRU
  k_gru<<<1024, 128, 0, stream>>>(x, wih, whh, bih, bhh, h);

  // Stage B: Laplacian (B1) and powers: B2=G, B3=G^32
  hipMemsetAsync(B1, 0, (size_t)1048576 * 4, stream);
  k_scatter<<<(E + 255) / 256, 256, 0, stream>>>(ei, ew, B1, E);
  k_degree<<<NN, 256, 0, stream>>>(B1, disq);
  k_lap<<<4096, 256, 0, stream>>>(B1, disq);
  k_mm_nt<<<dim3(16, 16), 256, 0, stream>>>(B1, B1, B2);  // G
  k_mm_nt<<<dim3(16, 16), 256, 0, stream>>>(B2, B2, B3);  // G^2
  k_mm_nt<<<dim3(16, 16), 256, 0, stream>>>(B3, B3, B1);  // G^4
  k_mm_nt<<<dim3(16, 16), 256, 0, stream>>>(B1, B1, B3);  // G^8
  k_mm_nt<<<dim3(16, 16), 256, 0, stream>>>(B3, B3, B1);  // G^16
  k_mm_nt<<<dim3(16, 16), 256, 0, stream>>>(B1, B1, B3);  // G^32

  // Stage C: 6 applies of G^32 (=192 powers), CholQR after each
  k_q0<<<192, 256, 0, stream>>>(Qa);
  for (int it = 0; it < 6; ++it) {
    float* src = (it & 1) ? Qb : Qa;
    float* dst = (it & 1) ? Qa : Qb;
    k_spmm<<<dim3(64, 4), 256, 0, stream>>>(B3, src, Zp);
    k_gram<<<32, 256, 0, stream>>>(Zp, dst, Sp);
    k_qr<<<4, 256, 0, stream>>>(Sp, dst);
  }
  // final orthonormal basis in Qa

  // Rayleigh-Ritz with G
  k_spmm<<<dim3(64, 4), 256, 0, stream>>>(B2, Qa, Zp);
  k_tbuild<<<32, 256, 0, stream>>>(Qa, Zp, Tp);
  k_jacobi<<<1, 384, 0, stream>>>(Tp, Vsel, s10);
  k_u10<<<4, 256, 0, stream>>>(Qa, Vsel, U10);

  // Stage D: conv layers (W folded into projection), out fused into last
  for (int l = 0; l < 3; ++l) {
    k_p0w<<<64, 320, 0, stream>>>(h, U10, convw + l * 1024, s10, P1);
    if (l < 2)
      k_update<0><<<dim3(64, 16), 256, 0, stream>>>(h, U10, P1, lw, lb, out);
    else
      k_update<1><<<dim3(64, 16), 256, 0, stream>>>(h, U10, P1, lw, lb, out);
  }
}